// Round 12
// baseline (328.334 us; speedup 1.0000x reference)
//
#include <hip/hip_runtime.h>
#include <hip/hip_bf16.h>
#include <type_traits>

#define LQ    900
#define BSZ   8
#define ROWS  (LQ*BSZ)        // 7200
#define CDIM  256
#define QKS   512             // merged q|k row stride
#define OAS   480             // merged off|aw row stride
#define NH    8
#define DH    32
#define LVTOT 21824
#define VROWS (LVTOT*BSZ)     // 174592
#define DFF   2048

typedef unsigned short u16;
typedef short short8 __attribute__((ext_vector_type(8)));
typedef float f32x4 __attribute__((ext_vector_type(4)));

__device__ __forceinline__ u16 f2bf(float f) {
    __hip_bfloat16 h = __float2bfloat16(f);
    return *reinterpret_cast<u16*>(&h);
}
#define ATTN_SCALE 0.1767766952966369f
// row-dependent chunk swizzle for BK=32 tiles (4 chunks of 16B per row)
#define SWZ(r) (((r) & 3) ^ (((r) >> 2) & 3))

// ---------------- elementwise add (float4) ----------------
__global__ __launch_bounds__(256) void addvec_kernel(const float* __restrict__ a,
                                                     const float* __restrict__ b,
                                                     float* __restrict__ c, int n4) {
    int i = blockIdx.x * 256 + threadIdx.x;
    if (i < n4) {
        float4 x = reinterpret_cast<const float4*>(a)[i];
        float4 y = reinterpret_cast<const float4*>(b)[i];
        reinterpret_cast<float4*>(c)[i] = make_float4(x.x+y.x, x.y+y.y, x.z+y.z, x.w+y.w);
    }
}

// ---------------- unified prep: 10 weight transposes (+scale) + bias concat ----------------
struct PrepArgs {
    const float* Wq; const float* Wk; const float* Wv; const float* Wo;
    const float* Wval; const float* Wout; const float* Woff; const float* Watt;
    const float* W1; const float* W2;
    u16* WqkT; u16* WvT; u16* WoT; u16* WvalT; u16* WoutT; u16* WoaT; u16* W1T; u16* W2T;
    const float* bq; const float* bk; const float* boff; const float* batt;
    float* bqk; float* boa;
};
__global__ __launch_bounds__(256) void prep_kernel(PrepArgs a) {
    __shared__ float t[32][33];
    const int id = blockIdx.x;
    if (id == 1528) {   // bias concat (scale folded into bq)
        const int tx = threadIdx.x;
        if (tx < 256) { a.bqk[tx] = a.bq[tx] * ATTN_SCALE; a.bqk[256 + tx] = a.bk[tx]; }
        for (int i = tx; i < 320; i += 256) a.boa[i] = a.boff[i];
        if (tx < 160) a.boa[320 + tx] = a.batt[tx];
        return;
    }
    const float* W; u16* Wt; int K = 256, N = 256, nx = 8; float scale = 1.f; int r;
    if      (id < 64)   { W = a.Wq;   Wt = a.WqkT;           scale = ATTN_SCALE; r = id; }
    else if (id < 128)  { W = a.Wk;   Wt = a.WqkT + 256*256; r = id - 64; }
    else if (id < 192)  { W = a.Wv;   Wt = a.WvT;            r = id - 128; }
    else if (id < 256)  { W = a.Wo;   Wt = a.WoT;            r = id - 192; }
    else if (id < 320)  { W = a.Wval; Wt = a.WvalT;          r = id - 256; }
    else if (id < 384)  { W = a.Wout; Wt = a.WoutT;          r = id - 320; }
    else if (id < 464)  { W = a.Woff; Wt = a.WoaT;           N = 320; nx = 10; r = id - 384; }
    else if (id < 504)  { W = a.Watt; Wt = a.WoaT + 320*256; N = 160; nx = 5;  r = id - 464; }
    else if (id < 1016) { W = a.W1;   Wt = a.W1T;            N = 2048; nx = 64; r = id - 504; }
    else                { W = a.W2;   Wt = a.W2T;            K = 2048; N = 256; nx = 8; r = id - 1016; }
    const int n0 = (r % nx) * 32, k0 = (r / nx) * 32;
    const int tx = threadIdx.x & 31, ty = threadIdx.x >> 5;
    #pragma unroll
    for (int rr = ty; rr < 32; rr += 8)
        t[rr][tx] = W[(size_t)(k0 + rr) * N + n0 + tx];
    __syncthreads();
    #pragma unroll
    for (int rr = ty; rr < 32; rr += 8)
        Wt[(size_t)(n0 + rr) * K + k0 + tx] = f2bf(t[tx][rr] * scale);
}

// ---------------- pipelined bf16 MFMA GEMM body ----------------
// 128x128 tile, BK=32, 512 threads (8 waves 2x4, 64x32 out/wave).
// A: global->reg (4 rotating sets, issued 3 steps ahead) -> ds_write 1 ahead.
// B: global_load_lds into 4-buffer LDS ring, issued 3 steps ahead.
// One raw s_barrier per step; counted vmcnt keeps 7 (f32) / 5 (bf16) loads in
// flight across barriers. LDS: A dbuf 16KB + B ring 32KB = 48KB.
template<typename AT, int RELU, typename OutT>
__device__ __forceinline__ void gemm_body(const AT* __restrict__ A,
                                          const u16* __restrict__ Wt,
                                          const float* __restrict__ bias,
                                          OutT* __restrict__ C,
                                          int M, int N, int K,
                                          int m0, int n0, int tid, u16* S) {
    const int lane = tid & 63;
    const int w = tid >> 6;
    const int wr = w >> 2, wc = w & 3;         // 2 x 4 wave grid
    const int lr = lane & 15, lg = lane >> 4;
    const int sr = tid >> 2, sc = tid & 3;
    const int ns = K >> 5;                     // always multiple of 4 here (8 or 64)
    const int arow = (m0 + sr < M) ? (m0 + sr) : (M - 1);
    int brow = n0 + sr; if (brow > N - 1) brow = N - 1;
    const u16* Bsrc = Wt + (size_t)brow * K + ((sc ^ SWZ(sr)) << 3);
    u16* Bdst = S + 8192 + ((tid & ~63) << 3);   // +buf*4096 (wave-uniform base)

    f32x4 acc[4][2] = {};
    float4 fal[4], fah[4];
    short8 fab[4];

#define LOADA(I, KK) do { \
    if constexpr (std::is_same<AT, float>::value) { \
        const float4* s_ = reinterpret_cast<const float4*>((const float*)A + (size_t)arow*K + (KK)*32 + sc*8); \
        fal[I] = s_[0]; fah[I] = s_[1]; \
    } else { \
        fab[I] = *reinterpret_cast<const short8*>((const u16*)A + (size_t)arow*K + (KK)*32 + sc*8); \
    } } while (0)

#define STAGEB(BUF, KK) \
    __builtin_amdgcn_global_load_lds((const __attribute__((address_space(1))) void*)(Bsrc + (size_t)(KK)*32), \
        (__attribute__((address_space(3))) void*)(Bdst + (BUF)*4096), 16, 0, 0)

#define WRITEA(BUF, I) do { \
    u16 t_[8]; \
    if constexpr (std::is_same<AT, float>::value) { \
        t_[0]=f2bf(fal[I].x); t_[1]=f2bf(fal[I].y); t_[2]=f2bf(fal[I].z); t_[3]=f2bf(fal[I].w); \
        t_[4]=f2bf(fah[I].x); t_[5]=f2bf(fah[I].y); t_[6]=f2bf(fah[I].z); t_[7]=f2bf(fah[I].w); \
    } else { *reinterpret_cast<short8*>(t_) = fab[I]; } \
    *reinterpret_cast<uint4*>(&S[(BUF)*4096 + sr*32 + ((sc ^ SWZ(sr)) * 8)]) = *reinterpret_cast<const uint4*>(t_); \
    } while (0)

#define WAITVM() do { \
    if constexpr (std::is_same<AT, float>::value) asm volatile("s_waitcnt vmcnt(7)" ::: "memory"); \
    else asm volatile("s_waitcnt vmcnt(5)" ::: "memory"); } while (0)

#define COMPUTE(CUR, BB) do { \
    short8 af_[4], bf_[2]; \
    _Pragma("unroll") for (int i = 0; i < 4; ++i) { \
        const int r_ = wr*64 + i*16 + lr; \
        af_[i] = *reinterpret_cast<const short8*>(&S[(CUR)*4096 + r_*32 + ((lg ^ SWZ(r_)) * 8)]); } \
    _Pragma("unroll") for (int j = 0; j < 2; ++j) { \
        const int rb_ = wc*32 + j*16 + lr; \
        bf_[j] = *reinterpret_cast<const short8*>(&S[8192 + (BB)*4096 + rb_*32 + ((lg ^ SWZ(rb_)) * 8)]); } \
    _Pragma("unroll") for (int i = 0; i < 4; ++i) \
        _Pragma("unroll") for (int j = 0; j < 2; ++j) \
            acc[i][j] = __builtin_amdgcn_mfma_f32_16x16x32_bf16(af_[i], bf_[j], acc[i][j], 0, 0, 0); \
    } while (0)

#define STEP(c) do { \
    asm volatile("s_waitcnt lgkmcnt(0)" ::: "memory"); \
    __builtin_amdgcn_s_barrier(); \
    int kp_ = k4 + (c) + 3; if (kp_ > ns - 1) kp_ = ns - 1; \
    LOADA(((c)+3)&3, kp_); STAGEB(((c)+3)&3, kp_); \
    WAITVM(); \
    WRITEA(((c)+1)&1, ((c)+1)&3); \
    COMPUTE((c)&1, (c)&3); } while (0)

    // prologue: fill 3-deep pipeline
    LOADA(0, 0); STAGEB(0, 0);
    LOADA(1, 1); STAGEB(1, 1);
    LOADA(2, 2); STAGEB(2, 2);
    WAITVM();
    WRITEA(0, 0);

    for (int q = 0; q < (ns >> 2); ++q) {
        const int k4 = q << 2;
        STEP(0); STEP(1); STEP(2); STEP(3);
    }
    // drain pending (redundant tail) loads before reusing S / exiting
    asm volatile("s_waitcnt vmcnt(0) lgkmcnt(0)" ::: "memory");
    __builtin_amdgcn_s_barrier();

#undef LOADA
#undef STAGEB
#undef WRITEA
#undef WAITVM
#undef COMPUTE
#undef STEP

    if constexpr (std::is_same<OutT, float>::value) {
        #pragma unroll
        for (int j = 0; j < 2; ++j) {
            const int col = n0 + wc*32 + j*16 + lr;
            if (col >= N) continue;
            const float bcol = bias[col];
            #pragma unroll
            for (int i = 0; i < 4; ++i) {
                #pragma unroll
                for (int r = 0; r < 4; ++r) {
                    const int row = m0 + wr*64 + i*16 + lg*4 + r;
                    if (row >= M) continue;
                    float v = acc[i][j][r] + bcol;
                    if (RELU) v = fmaxf(v, 0.f);
                    C[(size_t)row * N + col] = v;
                }
            }
        }
    } else {
        // LDS-staged coalesced bf16 epilogue (N multiple of 128 on this path)
        u16* Ct = S;   // 32KB of the 48KB
        #pragma unroll
        for (int j = 0; j < 2; ++j) {
            const int col = wc*32 + j*16 + lr;
            const float bcol = bias[n0 + col];
            #pragma unroll
            for (int i = 0; i < 4; ++i)
                #pragma unroll
                for (int r = 0; r < 4; ++r) {
                    float v = acc[i][j][r] + bcol;
                    if (RELU) v = fmaxf(v, 0.f);
                    Ct[(wr*64 + i*16 + lg*4 + r)*128 + col] = f2bf(v);
                }
        }
        __syncthreads();
        #pragma unroll
        for (int it = 0; it < 4; ++it) {
            const int idx = it*512 + tid;
            const int row = idx >> 4, cc = idx & 15;
            if (m0 + row < M)
                *reinterpret_cast<uint4*>(&C[(size_t)(m0 + row) * N + n0 + cc*8]) =
                    *reinterpret_cast<const uint4*>(&Ct[row*128 + cc*8]);
        }
    }
}

template<typename AT, int RELU, typename OutT>
__global__ __launch_bounds__(512) void gemm_mfma(const AT* __restrict__ A,
                                                 const u16* __restrict__ Wt,
                                                 const float* __restrict__ bias,
                                                 OutT* __restrict__ C, int M, int N, int K) {
    __shared__ __align__(16) u16 S[24576];
    gemm_body<AT, RELU, OutT>(A, Wt, bias, C, M, N, K,
                              blockIdx.y * 128, blockIdx.x * 128, threadIdx.x, S);
}

// merged value | qk | v dispatch (all K=256, f32 A, bf16 out) — one instantiation
__global__ __launch_bounds__(512) void mgemm3_kernel(
        const float* __restrict__ memory, const u16* __restrict__ WvalT, const float* __restrict__ bval, u16* __restrict__ Cval,
        const float* __restrict__ qkin,   const u16* __restrict__ WqkT,  const float* __restrict__ bqk,  u16* __restrict__ Cqk,
        const float* __restrict__ tgtv,   const u16* __restrict__ WvT,   const float* __restrict__ bv,   u16* __restrict__ Cv) {
    __shared__ __align__(16) u16 S[24576];
    int id = blockIdx.x;
    const float* A; const u16* Wt; const float* bias; u16* C; int M, N, m0, n0;
    if (id < 2728)      { A = memory; Wt = WvalT; bias = bval; C = Cval; M = VROWS; N = 256; m0 = (id >> 1)*128; n0 = (id & 1)*128; }
    else if (id < 2956) { id -= 2728; A = qkin; Wt = WqkT; bias = bqk; C = Cqk; M = ROWS; N = 512; m0 = (id >> 2)*128; n0 = (id & 3)*128; }
    else                { id -= 2956; A = tgtv; Wt = WvT; bias = bv; C = Cv; M = ROWS; N = 256; m0 = (id >> 1)*128; n0 = (id & 1)*128; }
    gemm_body<float, 0, u16>(A, Wt, bias, C, M, N, 256, m0, n0, threadIdx.x, S);
}

// ---------------- MFMA flash self-attention (bf16 q/k/v in) ----------------
__global__ __launch_bounds__(256) void attn_mfma_kernel(const u16* __restrict__ qkb,
                                                        const u16* __restrict__ vb,
                                                        float* __restrict__ out) {
    __shared__ __align__(16) u16 Ks[64*32];
    __shared__ __align__(16) u16 Vt[32*64];
    const int bx = blockIdx.x;
    const int qt = bx & 7, h = (bx >> 3) & 7, b = bx >> 6;
    const int tid = threadIdx.x;
    const int w = tid >> 6, lane = tid & 63;
    const int lr = lane & 15, lg = lane >> 4;
    const int m0 = qt*128 + w*32;

    short8 qf[2];
    #pragma unroll
    for (int j = 0; j < 2; ++j) {
        int lq = m0 + j*16 + lr; if (lq > LQ-1) lq = LQ-1;
        qf[j] = *reinterpret_cast<const short8*>(&qkb[((size_t)lq*BSZ + b)*QKS + h*DH + lg*8]);
    }

    f32x4 o00 = {}, o01 = {}, o10 = {}, o11 = {};
    float m[2] = {-1e30f, -1e30f}, l[2] = {0.f, 0.f};
    const f32x4 zero = {};

    for (int kt = 0; kt < 15; ++kt) {
        __syncthreads();
        {
            const int key = tid >> 2, c = tid & 3;
            int kg = kt*64 + key; if (kg > LQ-1) kg = LQ-1;
            *reinterpret_cast<short8*>(&Ks[key*32 + ((c ^ ((key>>1)&3)) * 8)]) =
                *reinterpret_cast<const short8*>(&qkb[((size_t)kg*BSZ + b)*QKS + 256 + h*DH + c*8]);
            short8 vv = *reinterpret_cast<const short8*>(&vb[((size_t)kg*BSZ + b)*CDIM + h*DH + c*8]);
            const u16* pv = reinterpret_cast<const u16*>(&vv);
            #pragma unroll
            for (int e = 0; e < 8; ++e) {
                const int dh = c*8 + e;
                Vt[dh*64 + (((key>>3) ^ (dh&7)) * 8) + (key&7)] = pv[e];
            }
        }
        __syncthreads();

        f32x4 s[4][2];
        #pragma unroll
        for (int i = 0; i < 4; ++i) {
            const int key = i*16 + lr;
            short8 kf = *reinterpret_cast<const short8*>(&Ks[key*32 + ((lg ^ ((key>>1)&3)) * 8)]);
            s[i][0] = __builtin_amdgcn_mfma_f32_16x16x32_bf16(kf, qf[0], zero, 0, 0, 0);
            s[i][1] = __builtin_amdgcn_mfma_f32_16x16x32_bf16(kf, qf[1], zero, 0, 0, 0);
        }
        const int lim = LQ - kt*64 - lg*4;
        #pragma unroll
        for (int i = 0; i < 4; ++i)
            #pragma unroll
            for (int r = 0; r < 4; ++r)
                if (i*16 + r >= lim) { s[i][0][r] = -1e30f; s[i][1][r] = -1e30f; }

        #pragma unroll
        for (int j = 0; j < 2; ++j) {
            float mx = -1e30f;
            #pragma unroll
            for (int i = 0; i < 4; ++i)
                #pragma unroll
                for (int r = 0; r < 4; ++r) mx = fmaxf(mx, s[i][j][r]);
            mx = fmaxf(mx, __shfl_xor(mx, 16));
            mx = fmaxf(mx, __shfl_xor(mx, 32));
            const float mn = fmaxf(m[j], mx);
            const float corr = __expf(m[j] - mn);
            float sum = 0.f;
            #pragma unroll
            for (int i = 0; i < 4; ++i)
                #pragma unroll
                for (int r = 0; r < 4; ++r) {
                    float p = __expf(s[i][j][r] - mn);
                    s[i][j][r] = p;
                    sum += p;
                }
            sum += __shfl_xor(sum, 16);
            sum += __shfl_xor(sum, 32);
            l[j] = l[j]*corr + sum;
            m[j] = mn;
            if (j == 0) { o00 *= corr; o10 *= corr; }
            else        { o01 *= corr; o11 *= corr; }
        }

        short8 pb[2][2];
        #pragma unroll
        for (int kh = 0; kh < 2; ++kh)
            #pragma unroll
            for (int j = 0; j < 2; ++j) {
                u16 t[8];
                #pragma unroll
                for (int e = 0; e < 4; ++e) {
                    t[e]   = f2bf(s[2*kh][j][e]);
                    t[e+4] = f2bf(s[2*kh+1][j][e]);
                }
                pb[kh][j] = *reinterpret_cast<short8*>(t);
            }

        #pragma unroll
        for (int ip = 0; ip < 2; ++ip) {
            const int dh = ip*16 + lr;
            #pragma unroll
            for (int kh = 0; kh < 2; ++kh) {
                u16 t[8];
                const int c0 = (kh*4 + (lg>>1)) ^ (dh&7);
                const int c1 = (kh*4 + 2 + (lg>>1)) ^ (dh&7);
                *reinterpret_cast<uint2*>(&t[0]) =
                    *reinterpret_cast<const uint2*>(&Vt[dh*64 + c0*8 + (lg&1)*4]);
                *reinterpret_cast<uint2*>(&t[4]) =
                    *reinterpret_cast<const uint2*>(&Vt[dh*64 + c1*8 + (lg&1)*4]);
                short8 vf = *reinterpret_cast<short8*>(t);
                if (ip == 0) {
                    o00 = __builtin_amdgcn_mfma_f32_16x16x32_bf16(vf, pb[kh][0], o00, 0, 0, 0);
                    o01 = __builtin_amdgcn_mfma_f32_16x16x32_bf16(vf, pb[kh][1], o01, 0, 0, 0);
                } else {
                    o10 = __builtin_amdgcn_mfma_f32_16x16x32_bf16(vf, pb[kh][0], o10, 0, 0, 0);
                    o11 = __builtin_amdgcn_mfma_f32_16x16x32_bf16(vf, pb[kh][1], o11, 0, 0, 0);
                }
            }
        }
    }

    #pragma unroll
    for (int j = 0; j < 2; ++j) {
        const int lq = m0 + j*16 + lr;
        if (lq >= LQ) continue;
        const float inv = 1.f / l[j];
        float* op = &out[((size_t)lq*BSZ + b)*CDIM + h*DH];
        #pragma unroll
        for (int r = 0; r < 4; ++r) {
            const f32x4& a0 = (j == 0) ? o00 : o01;
            const f32x4& a1 = (j == 0) ? o10 : o11;
            op[lg*4 + r]      = a0[r] * inv;
            op[16 + lg*4 + r] = a1[r] * inv;
        }
    }
}

// ---------------- fused residual + LayerNorm ----------------
__global__ __launch_bounds__(256) void ln_res_kernel(const float* __restrict__ xin,
                                                     const float* __restrict__ res,
                                                     const float* __restrict__ g,
                                                     const float* __restrict__ beta,
                                                     float* __restrict__ out) {
    const int row  = blockIdx.x * 4 + (threadIdx.x >> 6);
    const int lane = threadIdx.x & 63;
    const size_t base = (size_t)row * CDIM + lane * 4;
    float4 a = *reinterpret_cast<const float4*>(&xin[base]);
    float4 r = *reinterpret_cast<const float4*>(&res[base]);
    float x0 = a.x+r.x, x1 = a.y+r.y, x2 = a.z+r.z, x3 = a.w+r.w;
    float s = x0+x1+x2+x3;
    #pragma unroll
    for (int o = 1; o < 64; o <<= 1) s += __shfl_xor(s, o);
    float mean = s * (1.f/256.f);
    float d0 = x0-mean, d1 = x1-mean, d2 = x2-mean, d3 = x3-mean;
    float sq = d0*d0 + d1*d1 + d2*d2 + d3*d3;
    #pragma unroll
    for (int o = 1; o < 64; o <<= 1) sq += __shfl_xor(sq, o);
    float rs = rsqrtf(sq * (1.f/256.f) + 1e-5f);
    float4 gg = *reinterpret_cast<const float4*>(&g[lane*4]);
    float4 bb = *reinterpret_cast<const float4*>(&beta[lane*4]);
    float4 o4 = make_float4(d0*rs*gg.x+bb.x, d1*rs*gg.y+bb.y, d2*rs*gg.z+bb.z, d3*rs*gg.w+bb.w);
    *reinterpret_cast<float4*>(&out[base]) = o4;
}

// ---------------- softmax over 20 (in merged oab buffer, offset 320) ----------------
__global__ __launch_bounds__(256) void softmax20_kernel(float* __restrict__ oab) {
    int item = blockIdx.x * 256 + threadIdx.x;
    if (item >= ROWS * NH) return;
    int row = item >> 3, h = item & 7;
    float* p = &oab[(size_t)row*OAS + 320 + h*20];
    float mx = -1e30f;
    float e[20];
    #pragma unroll
    for (int j = 0; j < 20; ++j) mx = fmaxf(mx, p[j]);
    float sum = 0.f;
    #pragma unroll
    for (int j = 0; j < 20; ++j) { e[j] = __expf(p[j] - mx); sum += e[j]; }
    float inv = 1.f / sum;
    #pragma unroll
    for (int j = 0; j < 20; ++j) p[j] = e[j] * inv;
}

// ---------------- ms-deformable sampling ----------------
__global__ __launch_bounds__(256) void msdeform_kernel(const u16* __restrict__ value,
                                                       const float* __restrict__ oab,
                                                       const float* __restrict__ refp,
                                                       float* __restrict__ samp) {
    const int gid = blockIdx.x * 32 + (threadIdx.x >> 3);  // row*8 + h
    const int ch  = (threadIdx.x & 7) * 4;
    const int h   = gid & 7;
    const int row = gid >> 3;
    const int b   = row & 7;
    const int WL[5] = {128, 64, 32, 16, 8};
    const int SL[5] = {0, 16384, 20480, 21504, 21760};
    const u16* vbase = value + h*DH + ch;
    float a0 = 0.f, a1 = 0.f, a2 = 0.f, a3 = 0.f;
    #pragma unroll
    for (int l = 0; l < 5; ++l) {
        const float2 r2 = *reinterpret_cast<const float2*>(&refp[((size_t)row*5 + l)*2]);
        const int W = WL[l];
        const float Wf = (float)W;
        #pragma unroll
        for (int p = 0; p < 4; ++p) {
            const float2 o2 = *reinterpret_cast<const float2*>(&oab[(size_t)row*OAS + ((h*5 + l)*4 + p)*2]);
            const float aw = oab[(size_t)row*OAS + 320 + h*20 + l*4 + p];
            const float x = (r2.x + o2.x / Wf) * Wf - 0.5f;
            const float y = (r2.y + o2.y / Wf) * Wf - 0.5f;
            const float x0f = floorf(x), y0f = floorf(y);
            const float fx = x - x0f, fy = y - y0f;
            const int x0 = (int)x0f, y0 = (int)y0f;
            float wx0 = (1.f - fx) * aw, wx1 = fx * aw;
            float fy0 = 1.f - fy, fy1 = fy;
            if (x0 < 0 || x0 >= W)       wx0 = 0.f;
            if (x0+1 < 0 || x0+1 >= W)   wx1 = 0.f;
            if (y0 < 0 || y0 >= W)       fy0 = 0.f;
            if (y0+1 < 0 || y0+1 >= W)   fy1 = 0.f;
            const float w00 = wx0*fy0, w10 = wx1*fy0, w01 = wx0*fy1, w11 = wx1*fy1;
            const int xc0 = min(max(x0, 0), W-1),   xc1 = min(max(x0+1, 0), W-1);
            const int yc0 = min(max(y0, 0), W-1),   yc1 = min(max(y0+1, 0), W-1);
            const int r0 = SL[l] + yc0*W, r1 = SL[l] + yc1*W;
            const int o00i = ((r0 + xc0)*BSZ + b) * CDIM;
            const int o10i = ((r0 + xc1)*BSZ + b) * CDIM;
            const int o01i = ((r1 + xc0)*BSZ + b) * CDIM;
            const int o11i = ((r1 + xc1)*BSZ + b) * CDIM;
            const uint2 u00 = *reinterpret_cast<const uint2*>(vbase + o00i);
            const uint2 u10 = *reinterpret_cast<const uint2*>(vbase + o10i);
            const uint2 u01 = *reinterpret_cast<const uint2*>(vbase + o01i);
            const uint2 u11 = *reinterpret_cast<const uint2*>(vbase + o11i);
            a0 += w00 * __uint_as_float(u00.x << 16) + w10 * __uint_as_float(u10.x << 16)
                + w01 * __uint_as_float(u01.x << 16) + w11 * __uint_as_float(u11.x << 16);
            a1 += w00 * __uint_as_float(u00.x & 0xffff0000u) + w10 * __uint_as_float(u10.x & 0xffff0000u)
                + w01 * __uint_as_float(u01.x & 0xffff0000u) + w11 * __uint_as_float(u11.x & 0xffff0000u);
            a2 += w00 * __uint_as_float(u00.y << 16) + w10 * __uint_as_float(u10.y << 16)
                + w01 * __uint_as_float(u01.y << 16) + w11 * __uint_as_float(u11.y << 16);
            a3 += w00 * __uint_as_float(u00.y & 0xffff0000u) + w10 * __uint_as_float(u10.y & 0xffff0000u)
                + w01 * __uint_as_float(u01.y & 0xffff0000u) + w11 * __uint_as_float(u11.y & 0xffff0000u);
        }
    }
    float4 o4 = make_float4(a0, a1, a2, a3);
    *reinterpret_cast<float4*>(&samp[(size_t)row*CDIM + h*DH + ch]) = o4;
}

// ---------------- launch ----------------
extern "C" void kernel_launch(void* const* d_in, const int* in_sizes, int n_in,
                              void* d_out, int out_size, void* d_ws, size_t ws_size,
                              hipStream_t stream) {
    (void)in_sizes; (void)n_in; (void)out_size; (void)ws_size;
    const float* tgt    = (const float*)d_in[0];
    const float* qpos   = (const float*)d_in[1];
    const float* refpts = (const float*)d_in[2];
    const float* memory = (const float*)d_in[3];
    const float* Wq  = (const float*)d_in[6];
    const float* Wk  = (const float*)d_in[7];
    const float* Wv  = (const float*)d_in[8];
    const float* Wo  = (const float*)d_in[9];
    const float* Woff= (const float*)d_in[10];
    const float* Watt= (const float*)d_in[11];
    const float* Wval= (const float*)d_in[12];
    const float* Wout= (const float*)d_in[13];
    const float* W1  = (const float*)d_in[14];
    const float* W2  = (const float*)d_in[15];
    const float* bq  = (const float*)d_in[16];
    const float* bk  = (const float*)d_in[17];
    const float* bv  = (const float*)d_in[18];
    const float* bo  = (const float*)d_in[19];
    const float* boff= (const float*)d_in[20];
    const float* batt= (const float*)d_in[21];
    const float* bval= (const float*)d_in[22];
    const float* bout= (const float*)d_in[23];
    const float* b1  = (const float*)d_in[24];
    const float* b2  = (const float*)d_in[25];
    const float* ln1g= (const float*)d_in[26];
    const float* ln1b= (const float*)d_in[27];
    const float* ln2g= (const float*)d_in[28];
    const float* ln2b= (const float*)d_in[29];
    const float* ln3g= (const float*)d_in[30];
    const float* ln3b= (const float*)d_in[31];
    float* out = (float*)d_out;

    char* ws = (char*)d_ws;
    const size_t RB = (size_t)ROWS * CDIM * 4;     // 7.37 MB
    float* tgt2  = (float*)(ws + 0*RB);
    float* tgt3  = (float*)(ws + 1*RB);
    float* qk    = (float*)(ws + 2*RB);            // sa-o / ca-o
    float* vbuf  = (float*)(ws + 3*RB);            // samp
    float* abuf  = (float*)(ws + 4*RB);            // attn-out / ffn-out
    float* qkin  = (float*)(ws + 5*RB);            // tgt+qpos / tgt2+qpos
    u16* qkb = (u16*)(ws + 6*RB);                              // 7200x512 bf16
    u16* vb  = (u16*)(ws + 6*RB + (size_t)ROWS*QKS*2);         // 7200x256 bf16
    float* oab = (float*)(ws + 6*RB + (size_t)ROWS*QKS*2 + (size_t)ROWS*CDIM*2);   // 7200x480 f32
    char* wsm = ws + 6*RB + (size_t)ROWS*QKS*2 + (size_t)ROWS*CDIM*2 + (size_t)ROWS*OAS*4;
    u16* WqkT  = (u16*)(wsm);                       // 512x256
    u16* WvT   = (u16*)(wsm + 262144);
    u16* WoT   = (u16*)(wsm + 262144 + 1*131072);
    u16* WvalT = (u16*)(wsm + 262144 + 2*131072);
    u16* WoutT = (u16*)(wsm + 262144 + 3*131072);
    u16* WoaT  = (u16*)(wsm + 262144 + 4*131072);   // 480x256 (pad to 512 rows)
    u16* W1T   = (u16*)(wsm + 2*262144 + 4*131072);             // 2048x256
    u16* W2T   = (u16*)(wsm + 2*262144 + 4*131072 + 1048576);   // 256x2048
    float* bqk = (float*)(wsm + 2*262144 + 4*131072 + 2097152);
    float* boa = (float*)(wsm + 2*262144 + 4*131072 + 2097152 + 2048);
    char* big  = wsm + 2*262144 + 4*131072 + 2097152 + 4096;
    u16* valb  = (u16*)big;                         // 174592x256 bf16 (89.4MB)
    u16* ffnh  = (u16*)(big + (size_t)VROWS*CDIM*2);// 7200x2048 bf16

    const dim3 blk(256);
    const dim3 blk512(512);
    const int n4 = ROWS * CDIM / 4;

    // ---- prep: all weight transposes (scale folded into Wq/bq) + bias concat ----
    PrepArgs pa = { Wq, Wk, Wv, Wo, Wval, Wout, Woff, Watt, W1, W2,
                    WqkT, WvT, WoT, WvalT, WoutT, WoaT, W1T, W2T,
                    bq, bk, boff, batt, bqk, boa };
    prep_kernel<<<dim3(1529), blk, 0, stream>>>(pa);

    // ---- merged value | qk | v GEMMs ----
    addvec_kernel<<<dim3((n4+255)/256), blk, 0, stream>>>(tgt, qpos, qkin, n4);
    mgemm3_kernel<<<dim3(3070), blk512, 0, stream>>>(
        memory, WvalT, bval, valb,
        qkin, WqkT, bqk, qkb,
        tgt, WvT, bv, vb);

    // ---- stage 1: self-attention ----
    attn_mfma_kernel<<<dim3(512), blk, 0, stream>>>(qkb, vb, abuf);
    gemm_mfma<float,0,float><<<dim3(2,57), blk512, 0, stream>>>(abuf, WoT, bo, qk, ROWS, CDIM, CDIM);
    ln_res_kernel<<<dim3(ROWS/4), blk, 0, stream>>>(qk, tgt, ln2g, ln2b, tgt2);

    // ---- stage 2: deformable cross-attention ----
    addvec_kernel<<<dim3((n4+255)/256), blk, 0, stream>>>(tgt2, qpos, qkin, n4);
    gemm_mfma<float,0,float><<<dim3(4,57), blk512, 0, stream>>>(qkin, WoaT, boa, oab, ROWS, OAS, CDIM);
    softmax20_kernel<<<dim3((ROWS*NH+255)/256), blk, 0, stream>>>(oab);
    msdeform_kernel<<<dim3(ROWS*NH/32), blk, 0, stream>>>(valb, oab, refpts, vbuf);
    gemm_mfma<float,0,float><<<dim3(2,57), blk512, 0, stream>>>(vbuf, WoutT, bout, qk, ROWS, CDIM, CDIM);
    ln_res_kernel<<<dim3(ROWS/4), blk, 0, stream>>>(qk, tgt2, ln1g, ln1b, tgt3);

    // ---- stage 3: FFN ----
    gemm_mfma<float,1,u16><<<dim3(16,57), blk512, 0, stream>>>(tgt3, W1T, b1, ffnh, ROWS, DFF, CDIM);
    gemm_mfma<u16,0,float><<<dim3(2,57),  blk512, 0, stream>>>(ffnh, W2T, b2, abuf, ROWS, CDIM, DFF);
    ln_res_kernel<<<dim3(ROWS/4), blk, 0, stream>>>(abuf, tgt3, ln3g, ln3b, out);
}

// Round 13
// 320.874 us; speedup vs baseline: 1.0233x; 1.0233x over previous
//
#include <hip/hip_runtime.h>
#include <hip/hip_bf16.h>
#include <type_traits>

#define LQ    900
#define BSZ   8
#define ROWS  (LQ*BSZ)        // 7200
#define CDIM  256
#define QKS   512             // merged q|k row stride
#define OAS   480             // merged off|aw row stride
#define NH    8
#define DH    32
#define LVTOT 21824
#define VROWS (LVTOT*BSZ)     // 174592
#define DFF   2048

typedef unsigned short u16;
typedef short short8 __attribute__((ext_vector_type(8)));
typedef float f32x4 __attribute__((ext_vector_type(4)));

__device__ __forceinline__ u16 f2bf(float f) {
    __hip_bfloat16 h = __float2bfloat16(f);
    return *reinterpret_cast<u16*>(&h);
}
#define ATTN_SCALE 0.1767766952966369f
// row-dependent chunk swizzle for BK=32 tiles (4 chunks of 16B per row)
#define SWZ(r) (((r) & 3) ^ (((r) >> 2) & 3))

// ---------------- elementwise add (float4) ----------------
__global__ __launch_bounds__(256) void addvec_kernel(const float* __restrict__ a,
                                                     const float* __restrict__ b,
                                                     float* __restrict__ c, int n4) {
    int i = blockIdx.x * 256 + threadIdx.x;
    if (i < n4) {
        float4 x = reinterpret_cast<const float4*>(a)[i];
        float4 y = reinterpret_cast<const float4*>(b)[i];
        reinterpret_cast<float4*>(c)[i] = make_float4(x.x+y.x, x.y+y.y, x.z+y.z, x.w+y.w);
    }
}

// ---------------- unified prep: 10 weight transposes (+scale) + bias concat ----------------
struct PrepArgs {
    const float* Wq; const float* Wk; const float* Wv; const float* Wo;
    const float* Wval; const float* Wout; const float* Woff; const float* Watt;
    const float* W1; const float* W2;
    u16* WqkT; u16* WvT; u16* WoT; u16* WvalT; u16* WoutT; u16* WoaT; u16* W1T; u16* W2T;
    const float* bq; const float* bk; const float* boff; const float* batt;
    float* bqk; float* boa;
};
__global__ __launch_bounds__(256) void prep_kernel(PrepArgs a) {
    __shared__ float t[32][33];
    const int id = blockIdx.x;
    if (id == 1528) {   // bias concat (scale folded into bq)
        const int tx = threadIdx.x;
        if (tx < 256) { a.bqk[tx] = a.bq[tx] * ATTN_SCALE; a.bqk[256 + tx] = a.bk[tx]; }
        for (int i = tx; i < 320; i += 256) a.boa[i] = a.boff[i];
        if (tx < 160) a.boa[320 + tx] = a.batt[tx];
        return;
    }
    const float* W; u16* Wt; int K = 256, N = 256, nx = 8; float scale = 1.f; int r;
    if      (id < 64)   { W = a.Wq;   Wt = a.WqkT;           scale = ATTN_SCALE; r = id; }
    else if (id < 128)  { W = a.Wk;   Wt = a.WqkT + 256*256; r = id - 64; }
    else if (id < 192)  { W = a.Wv;   Wt = a.WvT;            r = id - 128; }
    else if (id < 256)  { W = a.Wo;   Wt = a.WoT;            r = id - 192; }
    else if (id < 320)  { W = a.Wval; Wt = a.WvalT;          r = id - 256; }
    else if (id < 384)  { W = a.Wout; Wt = a.WoutT;          r = id - 320; }
    else if (id < 464)  { W = a.Woff; Wt = a.WoaT;           N = 320; nx = 10; r = id - 384; }
    else if (id < 504)  { W = a.Watt; Wt = a.WoaT + 320*256; N = 160; nx = 5;  r = id - 464; }
    else if (id < 1016) { W = a.W1;   Wt = a.W1T;            N = 2048; nx = 64; r = id - 504; }
    else                { W = a.W2;   Wt = a.W2T;            K = 2048; N = 256; nx = 8; r = id - 1016; }
    const int n0 = (r % nx) * 32, k0 = (r / nx) * 32;
    const int tx = threadIdx.x & 31, ty = threadIdx.x >> 5;
    #pragma unroll
    for (int rr = ty; rr < 32; rr += 8)
        t[rr][tx] = W[(size_t)(k0 + rr) * N + n0 + tx];
    __syncthreads();
    #pragma unroll
    for (int rr = ty; rr < 32; rr += 8)
        Wt[(size_t)(n0 + rr) * K + k0 + tx] = f2bf(t[tx][rr] * scale);
}

// ---------------- shared staging helpers (BK=32) ----------------
// 128-row x 32-k bf16 tile via global_load_lds (per thread one 16B load)
__device__ __forceinline__ void stage512(const u16* __restrict__ src, u16* dst,
                                         int row0, int K, int k0, int maxrow, int tid) {
    const int sr = tid >> 2, sc = tid & 3;
    int grow = row0 + sr; if (grow > maxrow) grow = maxrow;
    const u16* gsrc = src + (size_t)grow * K + k0 + ((sc ^ SWZ(sr)) << 3);
    u16* ldst = dst + ((tid & ~63) << 3);
    __builtin_amdgcn_global_load_lds((const __attribute__((address_space(1))) void*)gsrc,
                                     (__attribute__((address_space(3))) void*)ldst, 16, 0, 0);
}

// ---------------- pipelined bf16 MFMA GEMM body (128x128 tile, counted vmcnt) ----------------
template<typename AT, int RELU, typename OutT>
__device__ __forceinline__ void gemm_body(const AT* __restrict__ A,
                                          const u16* __restrict__ Wt,
                                          const float* __restrict__ bias,
                                          OutT* __restrict__ C,
                                          int M, int N, int K,
                                          int m0, int n0, int tid, u16* S) {
    const int lane = tid & 63;
    const int w = tid >> 6;
    const int wr = w >> 2, wc = w & 3;         // 2 x 4 wave grid
    const int lr = lane & 15, lg = lane >> 4;
    const int sr = tid >> 2, sc = tid & 3;
    const int ns = K >> 5;                     // multiple of 4 here
    const int arow = (m0 + sr < M) ? (m0 + sr) : (M - 1);
    int brow = n0 + sr; if (brow > N - 1) brow = N - 1;
    const u16* Bsrc = Wt + (size_t)brow * K + ((sc ^ SWZ(sr)) << 3);
    u16* Bdst = S + 8192 + ((tid & ~63) << 3);

    f32x4 acc[4][2] = {};
    float4 fal[4], fah[4];
    short8 fab[4];

#define LOADA(I, KK) do { \
    if constexpr (std::is_same<AT, float>::value) { \
        const float4* s_ = reinterpret_cast<const float4*>((const float*)A + (size_t)arow*K + (KK)*32 + sc*8); \
        fal[I] = s_[0]; fah[I] = s_[1]; \
    } else { \
        fab[I] = *reinterpret_cast<const short8*>((const u16*)A + (size_t)arow*K + (KK)*32 + sc*8); \
    } } while (0)

#define STAGEB(BUF, KK) \
    __builtin_amdgcn_global_load_lds((const __attribute__((address_space(1))) void*)(Bsrc + (size_t)(KK)*32), \
        (__attribute__((address_space(3))) void*)(Bdst + (BUF)*4096), 16, 0, 0)

#define WRITEA(BUF, I) do { \
    u16 t_[8]; \
    if constexpr (std::is_same<AT, float>::value) { \
        t_[0]=f2bf(fal[I].x); t_[1]=f2bf(fal[I].y); t_[2]=f2bf(fal[I].z); t_[3]=f2bf(fal[I].w); \
        t_[4]=f2bf(fah[I].x); t_[5]=f2bf(fah[I].y); t_[6]=f2bf(fah[I].z); t_[7]=f2bf(fah[I].w); \
    } else { *reinterpret_cast<short8*>(t_) = fab[I]; } \
    *reinterpret_cast<uint4*>(&S[(BUF)*4096 + sr*32 + ((sc ^ SWZ(sr)) * 8)]) = *reinterpret_cast<const uint4*>(t_); \
    } while (0)

#define WAITVM() do { \
    if constexpr (std::is_same<AT, float>::value) asm volatile("s_waitcnt vmcnt(7)" ::: "memory"); \
    else asm volatile("s_waitcnt vmcnt(5)" ::: "memory"); } while (0)

#define COMPUTE(CUR, BB) do { \
    short8 af_[4], bf_[2]; \
    _Pragma("unroll") for (int i = 0; i < 4; ++i) { \
        const int r_ = wr*64 + i*16 + lr; \
        af_[i] = *reinterpret_cast<const short8*>(&S[(CUR)*4096 + r_*32 + ((lg ^ SWZ(r_)) * 8)]); } \
    _Pragma("unroll") for (int j = 0; j < 2; ++j) { \
        const int rb_ = wc*32 + j*16 + lr; \
        bf_[j] = *reinterpret_cast<const short8*>(&S[8192 + (BB)*4096 + rb_*32 + ((lg ^ SWZ(rb_)) * 8)]); } \
    _Pragma("unroll") for (int i = 0; i < 4; ++i) \
        _Pragma("unroll") for (int j = 0; j < 2; ++j) \
            acc[i][j] = __builtin_amdgcn_mfma_f32_16x16x32_bf16(af_[i], bf_[j], acc[i][j], 0, 0, 0); \
    } while (0)

#define STEP(c) do { \
    asm volatile("s_waitcnt lgkmcnt(0)" ::: "memory"); \
    __builtin_amdgcn_s_barrier(); \
    int kp_ = k4 + (c) + 3; if (kp_ > ns - 1) kp_ = ns - 1; \
    LOADA(((c)+3)&3, kp_); STAGEB(((c)+3)&3, kp_); \
    WAITVM(); \
    WRITEA(((c)+1)&1, ((c)+1)&3); \
    COMPUTE((c)&1, (c)&3); } while (0)

    LOADA(0, 0); STAGEB(0, 0);
    LOADA(1, 1); STAGEB(1, 1);
    LOADA(2, 2); STAGEB(2, 2);
    WAITVM();
    WRITEA(0, 0);

    for (int q = 0; q < (ns >> 2); ++q) {
        const int k4 = q << 2;
        STEP(0); STEP(1); STEP(2); STEP(3);
    }
    asm volatile("s_waitcnt vmcnt(0) lgkmcnt(0)" ::: "memory");
    __builtin_amdgcn_s_barrier();

#undef LOADA
#undef STAGEB
#undef WRITEA
#undef WAITVM
#undef COMPUTE
#undef STEP

    if constexpr (std::is_same<OutT, float>::value) {
        #pragma unroll
        for (int j = 0; j < 2; ++j) {
            const int col = n0 + wc*32 + j*16 + lr;
            if (col >= N) continue;
            const float bcol = bias[col];
            #pragma unroll
            for (int i = 0; i < 4; ++i) {
                #pragma unroll
                for (int r = 0; r < 4; ++r) {
                    const int row = m0 + wr*64 + i*16 + lg*4 + r;
                    if (row >= M) continue;
                    float v = acc[i][j][r] + bcol;
                    if (RELU) v = fmaxf(v, 0.f);
                    C[(size_t)row * N + col] = v;
                }
            }
        }
    } else {
        // LDS-staged coalesced bf16 epilogue; stride 136 breaks the 4-way bank conflict
        u16* Ct = S;
        #pragma unroll
        for (int j = 0; j < 2; ++j) {
            const int col = wc*32 + j*16 + lr;
            const float bcol = bias[n0 + col];
            #pragma unroll
            for (int i = 0; i < 4; ++i)
                #pragma unroll
                for (int r = 0; r < 4; ++r) {
                    float v = acc[i][j][r] + bcol;
                    if (RELU) v = fmaxf(v, 0.f);
                    Ct[(wr*64 + i*16 + lg*4 + r)*136 + col] = f2bf(v);
                }
        }
        __syncthreads();
        #pragma unroll
        for (int it = 0; it < 4; ++it) {
            const int idx = it*512 + tid;
            const int row = idx >> 4, cc = idx & 15;
            if (m0 + row < M)
                *reinterpret_cast<uint4*>(&C[(size_t)(m0 + row) * N + n0 + cc*8]) =
                    *reinterpret_cast<const uint4*>(&Ct[row*136 + cc*8]);
        }
    }
}

template<typename AT, int RELU, typename OutT>
__global__ __launch_bounds__(512) void gemm_mfma(const AT* __restrict__ A,
                                                 const u16* __restrict__ Wt,
                                                 const float* __restrict__ bias,
                                                 OutT* __restrict__ C, int M, int N, int K) {
    __shared__ __align__(16) u16 S[24576];
    gemm_body<AT, RELU, OutT>(A, Wt, bias, C, M, N, K,
                              blockIdx.y * 128, blockIdx.x * 128, threadIdx.x, S);
}

// merged value | qk | v dispatch. Value section uses an XCD-pairing swizzle:
// slots s and s+8 (same XCD under round-robin %8) map to the two column tiles
// of the same row tile -> A-tile re-read hits that XCD's L2.
__global__ __launch_bounds__(512) void mgemm3_kernel(
        const float* __restrict__ memory, const u16* __restrict__ WvalT, const float* __restrict__ bval, u16* __restrict__ Cval,
        const float* __restrict__ qkin,   const u16* __restrict__ WqkT,  const float* __restrict__ bqk,  u16* __restrict__ Cqk,
        const float* __restrict__ tgtv,   const u16* __restrict__ WvT,   const float* __restrict__ bv,   u16* __restrict__ Cv) {
    __shared__ __align__(16) u16 S[24576];
    int id = blockIdx.x;
    if (id < 2728) {
        int pair, half;
        if (id < 2720) { pair = (id >> 4) * 8 + (id & 7); half = (id >> 3) & 1; }
        else           { int i = id - 2720; pair = 1360 + (i & 3); half = i >> 2; }
        gemm_body<float, 0, u16>(memory, WvalT, bval, Cval, VROWS, 256, 256,
                                 pair * 128, half * 128, threadIdx.x, S);
    } else if (id < 2956) {
        id -= 2728;
        gemm_body<float, 0, u16>(qkin, WqkT, bqk, Cqk, ROWS, 512, 256,
                                 (id >> 2) * 128, (id & 3) * 128, threadIdx.x, S);
    } else {
        id -= 2956;
        gemm_body<float, 0, u16>(tgtv, WvT, bv, Cv, ROWS, 256, 256,
                                 (id >> 1) * 128, (id & 1) * 128, threadIdx.x, S);
    }
}

// ---------------- GEMM + residual + LayerNorm fused (N=256 fixed) ----------------
// 64-row x 256-col blocks, 512 threads, 8 waves of 64x32, BK=32, classic dbuf.
// out = LN(A@Wt + bias + res) * g + beta.
template<typename AT>
__global__ __launch_bounds__(512) void gemmln_kernel(const AT* __restrict__ A,
        const u16* __restrict__ Wt, const float* __restrict__ bias,
        const float* __restrict__ res, const float* __restrict__ g,
        const float* __restrict__ beta, float* __restrict__ out,
        int M, int K) {
    __shared__ __align__(16) u16 S[20480];   // A0[0,2048) A1[2048,4096) B0[4096,12288) B1[12288,20480)
    const int tid = threadIdx.x;
    const int lane = tid & 63;
    const int wv = tid >> 6;                 // 0..7 (column wave)
    const int lr = lane & 15, lg = lane >> 4;
    const int m0 = blockIdx.x * 64;
    const int ns = K >> 5;
    // A f32 reg-staging coords (8 threads/row, 16B each)
    const int asr = tid >> 3, asc = tid & 7;
    const int afrow = (m0 + asr < M) ? (m0 + asr) : (M - 1);
    // A bf16 lds-staging coords (waves 0-3)
    const int bsr = tid >> 2, bsc = tid & 3;
    const int abrow = (m0 + bsr < M) ? (m0 + bsr) : (M - 1);

    f32x4 acc[4][2] = {};
    float4 fa;

    auto stageB = [&](int buf, int k0) {
        stage512(Wt, S + 4096 + buf*8192,        0,   K, k0, 255, tid);
        stage512(Wt, S + 4096 + buf*8192 + 4096, 128, K, k0, 255, tid);
    };
    auto loadA = [&](int k0) {
        if constexpr (std::is_same<AT, float>::value)
            fa = *reinterpret_cast<const float4*>((const float*)A + (size_t)afrow*K + k0 + asc*4);
    };
    auto putA = [&](int buf, int k0) {
        if constexpr (std::is_same<AT, float>::value) {
            u16 t[4] = { f2bf(fa.x), f2bf(fa.y), f2bf(fa.z), f2bf(fa.w) };
            *reinterpret_cast<uint2*>(&S[buf*2048 + asr*32 + (((asc>>1) ^ SWZ(asr)) * 8) + (asc&1)*4]) =
                *reinterpret_cast<const uint2*>(t);
        } else {
            if (wv < 4) {
                const u16* gsrc = (const u16*)A + (size_t)abrow*K + k0 + ((bsc ^ SWZ(bsr)) << 3);
                u16* ldst = S + buf*2048 + ((tid & ~63) << 3);
                __builtin_amdgcn_global_load_lds((const __attribute__((address_space(1))) void*)gsrc,
                                                 (__attribute__((address_space(3))) void*)ldst, 16, 0, 0);
            }
        }
    };

    // prologue
    stageB(0, 0);
    loadA(0);
    if constexpr (std::is_same<AT, float>::value) putA(0, 0); else putA(0, 0);
    __syncthreads();

    for (int t = 0; t < ns; ++t) {
        const int cur = t & 1, nxt = cur ^ 1;
        if (t + 1 < ns) {
            stageB(nxt, (t+1) << 5);
            if constexpr (std::is_same<AT, float>::value) loadA((t+1) << 5);
            else putA(nxt, (t+1) << 5);
        }
        short8 af[4], bf[2];
        #pragma unroll
        for (int i = 0; i < 4; ++i) {
            const int r = i*16 + lr;
            af[i] = *reinterpret_cast<const short8*>(&S[cur*2048 + r*32 + ((lg ^ SWZ(r)) * 8)]);
        }
        #pragma unroll
        for (int j = 0; j < 2; ++j) {
            const int rb = wv*32 + j*16 + lr;
            bf[j] = *reinterpret_cast<const short8*>(&S[4096 + cur*8192 + rb*32 + ((lg ^ SWZ(rb)) * 8)]);
        }
        #pragma unroll
        for (int i = 0; i < 4; ++i)
            #pragma unroll
            for (int j = 0; j < 2; ++j)
                acc[i][j] = __builtin_amdgcn_mfma_f32_16x16x32_bf16(af[i], bf[j], acc[i][j], 0, 0, 0);
        if (t + 1 < ns) {
            if constexpr (std::is_same<AT, float>::value) putA(nxt, 0);
        }
        __syncthreads();
    }

    // ---- LN epilogue: v = acc + bias + res; row mean/var over 256 cols ----
    float* P = reinterpret_cast<float*>(S);          // [64 rows][8 waves][2]
    float* P2 = P + 1024;                            // [64 rows][2] mean/rstd
    const float bc0 = bias[wv*32 + lr], bc1 = bias[wv*32 + 16 + lr];
    #pragma unroll
    for (int i = 0; i < 4; ++i) {
        #pragma unroll
        for (int rr = 0; rr < 4; ++rr) {
            const int r16 = i*16 + lg*4 + rr;
            int grow = m0 + r16; if (grow > M - 1) grow = M - 1;
            float s1 = 0.f, s2 = 0.f;
            #pragma unroll
            for (int j = 0; j < 2; ++j) {
                const int col = wv*32 + j*16 + lr;
                float v = acc[i][j][rr] + (j ? bc1 : bc0) + res[(size_t)grow*CDIM + col];
                acc[i][j][rr] = v;
                s1 += v; s2 += v*v;
            }
            #pragma unroll
            for (int o = 1; o < 16; o <<= 1) {
                s1 += __shfl_xor(s1, o);
                s2 += __shfl_xor(s2, o);
            }
            if (lr == 0) {
                P[(r16*8 + wv)*2 + 0] = s1;
                P[(r16*8 + wv)*2 + 1] = s2;
            }
        }
    }
    __syncthreads();
    if (tid < 64) {
        float s1 = 0.f, s2 = 0.f;
        #pragma unroll
        for (int ww = 0; ww < 8; ++ww) {
            s1 += P[(tid*8 + ww)*2 + 0];
            s2 += P[(tid*8 + ww)*2 + 1];
        }
        const float mean = s1 * (1.f/256.f);
        const float var  = s2 * (1.f/256.f) - mean*mean;
        P2[tid*2 + 0] = mean;
        P2[tid*2 + 1] = rsqrtf(var + 1e-5f);
    }
    __syncthreads();
    const float g0 = g[wv*32 + lr],    g1 = g[wv*32 + 16 + lr];
    const float e0 = beta[wv*32 + lr], e1 = beta[wv*32 + 16 + lr];
    #pragma unroll
    for (int i = 0; i < 4; ++i)
        #pragma unroll
        for (int rr = 0; rr < 4; ++rr) {
            const int r16 = i*16 + lg*4 + rr;
            const int grow = m0 + r16;
            if (grow >= M) continue;
            const float mean = P2[r16*2], rstd = P2[r16*2 + 1];
            #pragma unroll
            for (int j = 0; j < 2; ++j) {
                const int col = wv*32 + j*16 + lr;
                out[(size_t)grow*CDIM + col] =
                    (acc[i][j][rr] - mean) * rstd * (j ? g1 : g0) + (j ? e1 : e0);
            }
        }
}

// ---------------- MFMA flash self-attention (bf16 q/k/v in) ----------------
__global__ __launch_bounds__(256) void attn_mfma_kernel(const u16* __restrict__ qkb,
                                                        const u16* __restrict__ vb,
                                                        float* __restrict__ out) {
    __shared__ __align__(16) u16 Ks[64*32];
    __shared__ __align__(16) u16 Vt[32*64];
    const int bx = blockIdx.x;
    const int qt = bx & 7, h = (bx >> 3) & 7, b = bx >> 6;
    const int tid = threadIdx.x;
    const int w = tid >> 6, lane = tid & 63;
    const int lr = lane & 15, lg = lane >> 4;
    const int m0 = qt*128 + w*32;

    short8 qf[2];
    #pragma unroll
    for (int j = 0; j < 2; ++j) {
        int lq = m0 + j*16 + lr; if (lq > LQ-1) lq = LQ-1;
        qf[j] = *reinterpret_cast<const short8*>(&qkb[((size_t)lq*BSZ + b)*QKS + h*DH + lg*8]);
    }

    f32x4 o00 = {}, o01 = {}, o10 = {}, o11 = {};
    float m[2] = {-1e30f, -1e30f}, l[2] = {0.f, 0.f};
    const f32x4 zero = {};

    for (int kt = 0; kt < 15; ++kt) {
        __syncthreads();
        {
            const int key = tid >> 2, c = tid & 3;
            int kg = kt*64 + key; if (kg > LQ-1) kg = LQ-1;
            *reinterpret_cast<short8*>(&Ks[key*32 + ((c ^ ((key>>1)&3)) * 8)]) =
                *reinterpret_cast<const short8*>(&qkb[((size_t)kg*BSZ + b)*QKS + 256 + h*DH + c*8]);
            short8 vv = *reinterpret_cast<const short8*>(&vb[((size_t)kg*BSZ + b)*CDIM + h*DH + c*8]);
            const u16* pv = reinterpret_cast<const u16*>(&vv);
            #pragma unroll
            for (int e = 0; e < 8; ++e) {
                const int dh = c*8 + e;
                Vt[dh*64 + (((key>>3) ^ (dh&7)) * 8) + (key&7)] = pv[e];
            }
        }
        __syncthreads();

        f32x4 s[4][2];
        #pragma unroll
        for (int i = 0; i < 4; ++i) {
            const int key = i*16 + lr;
            short8 kf = *reinterpret_cast<const short8*>(&Ks[key*32 + ((lg ^ ((key>>1)&3)) * 8)]);
            s[i][0] = __builtin_amdgcn_mfma_f32_16x16x32_bf16(kf, qf[0], zero, 0, 0, 0);
            s[i][1] = __builtin_amdgcn_mfma_f32_16x16x32_bf16(kf, qf[1], zero, 0, 0, 0);
        }
        const int lim = LQ - kt*64 - lg*4;
        #pragma unroll
        for (int i = 0; i < 4; ++i)
            #pragma unroll
            for (int r = 0; r < 4; ++r)
                if (i*16 + r >= lim) { s[i][0][r] = -1e30f; s[i][1][r] = -1e30f; }

        #pragma unroll
        for (int j = 0; j < 2; ++j) {
            float mx = -1e30f;
            #pragma unroll
            for (int i = 0; i < 4; ++i)
                #pragma unroll
                for (int r = 0; r < 4; ++r) mx = fmaxf(mx, s[i][j][r]);
            mx = fmaxf(mx, __shfl_xor(mx, 16));
            mx = fmaxf(mx, __shfl_xor(mx, 32));
            const float mn = fmaxf(m[j], mx);
            const float corr = __expf(m[j] - mn);
            float sum = 0.f;
            #pragma unroll
            for (int i = 0; i < 4; ++i)
                #pragma unroll
                for (int r = 0; r < 4; ++r) {
                    float p = __expf(s[i][j][r] - mn);
                    s[i][j][r] = p;
                    sum += p;
                }
            sum += __shfl_xor(sum, 16);
            sum += __shfl_xor(sum, 32);
            l[j] = l[j]*corr + sum;
            m[j] = mn;
            if (j == 0) { o00 *= corr; o10 *= corr; }
            else        { o01 *= corr; o11 *= corr; }
        }

        short8 pb[2][2];
        #pragma unroll
        for (int kh = 0; kh < 2; ++kh)
            #pragma unroll
            for (int j = 0; j < 2; ++j) {
                u16 t[8];
                #pragma unroll
                for (int e = 0; e < 4; ++e) {
                    t[e]   = f2bf(s[2*kh][j][e]);
                    t[e+4] = f2bf(s[2*kh+1][j][e]);
                }
                pb[kh][j] = *reinterpret_cast<short8*>(t);
            }

        #pragma unroll
        for (int ip = 0; ip < 2; ++ip) {
            const int dh = ip*16 + lr;
            #pragma unroll
            for (int kh = 0; kh < 2; ++kh) {
                u16 t[8];
                const int c0 = (kh*4 + (lg>>1)) ^ (dh&7);
                const int c1 = (kh*4 + 2 + (lg>>1)) ^ (dh&7);
                *reinterpret_cast<uint2*>(&t[0]) =
                    *reinterpret_cast<const uint2*>(&Vt[dh*64 + c0*8 + (lg&1)*4]);
                *reinterpret_cast<uint2*>(&t[4]) =
                    *reinterpret_cast<const uint2*>(&Vt[dh*64 + c1*8 + (lg&1)*4]);
                short8 vf = *reinterpret_cast<short8*>(t);
                if (ip == 0) {
                    o00 = __builtin_amdgcn_mfma_f32_16x16x32_bf16(vf, pb[kh][0], o00, 0, 0, 0);
                    o01 = __builtin_amdgcn_mfma_f32_16x16x32_bf16(vf, pb[kh][1], o01, 0, 0, 0);
                } else {
                    o10 = __builtin_amdgcn_mfma_f32_16x16x32_bf16(vf, pb[kh][0], o10, 0, 0, 0);
                    o11 = __builtin_amdgcn_mfma_f32_16x16x32_bf16(vf, pb[kh][1], o11, 0, 0, 0);
                }
            }
        }
    }

    #pragma unroll
    for (int j = 0; j < 2; ++j) {
        const int lq = m0 + j*16 + lr;
        if (lq >= LQ) continue;
        const float inv = 1.f / l[j];
        float* op = &out[((size_t)lq*BSZ + b)*CDIM + h*DH];
        #pragma unroll
        for (int r = 0; r < 4; ++r) {
            const f32x4& a0 = (j == 0) ? o00 : o01;
            const f32x4& a1 = (j == 0) ? o10 : o11;
            op[lg*4 + r]      = a0[r] * inv;
            op[16 + lg*4 + r] = a1[r] * inv;
        }
    }
}

// ---------------- ms-deformable sampling (softmax fused) ----------------
__global__ __launch_bounds__(256) void msdeform_kernel(const u16* __restrict__ value,
                                                       const float* __restrict__ oab,
                                                       const float* __restrict__ refp,
                                                       float* __restrict__ samp) {
    const int gid = blockIdx.x * 32 + (threadIdx.x >> 3);  // row*8 + h
    const int ch  = (threadIdx.x & 7) * 4;
    const int h   = gid & 7;
    const int row = gid >> 3;
    const int b   = row & 7;
    const int WL[5] = {128, 64, 32, 16, 8};
    const int SL[5] = {0, 16384, 20480, 21504, 21760};
    const u16* vbase = value + h*DH + ch;
    // fused softmax over 20 raw scores
    float e20[20];
    {
        const float* sp = &oab[(size_t)row*OAS + 320 + h*20];
        float mx = -1e30f;
        #pragma unroll
        for (int j = 0; j < 20; ++j) { e20[j] = sp[j]; mx = fmaxf(mx, e20[j]); }
        float sum = 0.f;
        #pragma unroll
        for (int j = 0; j < 20; ++j) { e20[j] = __expf(e20[j] - mx); sum += e20[j]; }
        const float inv = 1.f / sum;
        #pragma unroll
        for (int j = 0; j < 20; ++j) e20[j] *= inv;
    }
    float a0 = 0.f, a1 = 0.f, a2 = 0.f, a3 = 0.f;
    #pragma unroll
    for (int l = 0; l < 5; ++l) {
        const float2 r2 = *reinterpret_cast<const float2*>(&refp[((size_t)row*5 + l)*2]);
        const int W = WL[l];
        const float Wf = (float)W;
        #pragma unroll
        for (int p = 0; p < 4; ++p) {
            const float2 o2 = *reinterpret_cast<const float2*>(&oab[(size_t)row*OAS + ((h*5 + l)*4 + p)*2]);
            const float aw = e20[l*4 + p];
            const float x = (r2.x + o2.x / Wf) * Wf - 0.5f;
            const float y = (r2.y + o2.y / Wf) * Wf - 0.5f;
            const float x0f = floorf(x), y0f = floorf(y);
            const float fx = x - x0f, fy = y - y0f;
            const int x0 = (int)x0f, y0 = (int)y0f;
            float wx0 = (1.f - fx) * aw, wx1 = fx * aw;
            float fy0 = 1.f - fy, fy1 = fy;
            if (x0 < 0 || x0 >= W)       wx0 = 0.f;
            if (x0+1 < 0 || x0+1 >= W)   wx1 = 0.f;
            if (y0 < 0 || y0 >= W)       fy0 = 0.f;
            if (y0+1 < 0 || y0+1 >= W)   fy1 = 0.f;
            const float w00 = wx0*fy0, w10 = wx1*fy0, w01 = wx0*fy1, w11 = wx1*fy1;
            const int xc0 = min(max(x0, 0), W-1),   xc1 = min(max(x0+1, 0), W-1);
            const int yc0 = min(max(y0, 0), W-1),   yc1 = min(max(y0+1, 0), W-1);
            const int r0 = SL[l] + yc0*W, r1 = SL[l] + yc1*W;
            const int o00i = ((r0 + xc0)*BSZ + b) * CDIM;
            const int o10i = ((r0 + xc1)*BSZ + b) * CDIM;
            const int o01i = ((r1 + xc0)*BSZ + b) * CDIM;
            const int o11i = ((r1 + xc1)*BSZ + b) * CDIM;
            const uint2 u00 = *reinterpret_cast<const uint2*>(vbase + o00i);
            const uint2 u10 = *reinterpret_cast<const uint2*>(vbase + o10i);
            const uint2 u01 = *reinterpret_cast<const uint2*>(vbase + o01i);
            const uint2 u11 = *reinterpret_cast<const uint2*>(vbase + o11i);
            a0 += w00 * __uint_as_float(u00.x << 16) + w10 * __uint_as_float(u10.x << 16)
                + w01 * __uint_as_float(u01.x << 16) + w11 * __uint_as_float(u11.x << 16);
            a1 += w00 * __uint_as_float(u00.x & 0xffff0000u) + w10 * __uint_as_float(u10.x & 0xffff0000u)
                + w01 * __uint_as_float(u01.x & 0xffff0000u) + w11 * __uint_as_float(u11.x & 0xffff0000u);
            a2 += w00 * __uint_as_float(u00.y << 16) + w10 * __uint_as_float(u10.y << 16)
                + w01 * __uint_as_float(u01.y << 16) + w11 * __uint_as_float(u11.y << 16);
            a3 += w00 * __uint_as_float(u00.y & 0xffff0000u) + w10 * __uint_as_float(u10.y & 0xffff0000u)
                + w01 * __uint_as_float(u01.y & 0xffff0000u) + w11 * __uint_as_float(u11.y & 0xffff0000u);
        }
    }
    float4 o4 = make_float4(a0, a1, a2, a3);
    *reinterpret_cast<float4*>(&samp[(size_t)row*CDIM + h*DH + ch]) = o4;
}

// ---------------- launch ----------------
extern "C" void kernel_launch(void* const* d_in, const int* in_sizes, int n_in,
                              void* d_out, int out_size, void* d_ws, size_t ws_size,
                              hipStream_t stream) {
    (void)in_sizes; (void)n_in; (void)out_size; (void)ws_size;
    const float* tgt    = (const float*)d_in[0];
    const float* qpos   = (const float*)d_in[1];
    const float* refpts = (const float*)d_in[2];
    const float* memory = (const float*)d_in[3];
    const float* Wq  = (const float*)d_in[6];
    const float* Wk  = (const float*)d_in[7];
    const float* Wv  = (const float*)d_in[8];
    const float* Wo  = (const float*)d_in[9];
    const float* Woff= (const float*)d_in[10];
    const float* Watt= (const float*)d_in[11];
    const float* Wval= (const float*)d_in[12];
    const float* Wout= (const float*)d_in[13];
    const float* W1  = (const float*)d_in[14];
    const float* W2  = (const float*)d_in[15];
    const float* bq  = (const float*)d_in[16];
    const float* bk  = (const float*)d_in[17];
    const float* bv  = (const float*)d_in[18];
    const float* bo  = (const float*)d_in[19];
    const float* boff= (const float*)d_in[20];
    const float* batt= (const float*)d_in[21];
    const float* bval= (const float*)d_in[22];
    const float* bout= (const float*)d_in[23];
    const float* b1  = (const float*)d_in[24];
    const float* b2  = (const float*)d_in[25];
    const float* ln1g= (const float*)d_in[26];
    const float* ln1b= (const float*)d_in[27];
    const float* ln2g= (const float*)d_in[28];
    const float* ln2b= (const float*)d_in[29];
    const float* ln3g= (const float*)d_in[30];
    const float* ln3b= (const float*)d_in[31];
    float* out = (float*)d_out;

    char* ws = (char*)d_ws;
    const size_t RB = (size_t)ROWS * CDIM * 4;     // 7.37 MB
    float* tgt2  = (float*)(ws + 0*RB);
    float* tgt3  = (float*)(ws + 1*RB);
    float* vbuf  = (float*)(ws + 2*RB);            // samp
    float* abuf  = (float*)(ws + 3*RB);            // attn-out
    float* qkin  = (float*)(ws + 4*RB);            // tgt+qpos / tgt2+qpos
    u16* qkb = (u16*)(ws + 5*RB);                              // 7200x512 bf16
    u16* vb  = (u16*)(ws + 5*RB + (size_t)ROWS*QKS*2);         // 7200x256 bf16
    float* oab = (float*)(ws + 5*RB + (size_t)ROWS*QKS*2 + (size_t)ROWS*CDIM*2);   // 7200x480 f32
    char* wsm = ws + 5*RB + (size_t)ROWS*QKS*2 + (size_t)ROWS*CDIM*2 + (size_t)ROWS*OAS*4;
    u16* WqkT  = (u16*)(wsm);                       // 512x256
    u16* WvT   = (u16*)(wsm + 262144);
    u16* WoT   = (u16*)(wsm + 262144 + 1*131072);
    u16* WvalT = (u16*)(wsm + 262144 + 2*131072);
    u16* WoutT = (u16*)(wsm + 262144 + 3*131072);
    u16* WoaT  = (u16*)(wsm + 262144 + 4*131072);   // 480x256 (pad to 512 rows)
    u16* W1T   = (u16*)(wsm + 2*262144 + 4*131072);             // 2048x256
    u16* W2T   = (u16*)(wsm + 2*262144 + 4*131072 + 1048576);   // 256x2048
    float* bqk = (float*)(wsm + 2*262144 + 4*131072 + 2097152);
    float* boa = (float*)(wsm + 2*262144 + 4*131072 + 2097152 + 2048);
    char* big  = wsm + 2*262144 + 4*131072 + 2097152 + 4096;
    u16* valb  = (u16*)big;                         // 174592x256 bf16 (89.4MB)
    u16* ffnh  = (u16*)(big + (size_t)VROWS*CDIM*2);// 7200x2048 bf16

    const dim3 blk(256);
    const dim3 blk512(512);
    const int n4 = ROWS * CDIM / 4;

    // ---- prep: all weight transposes (scale folded into Wq/bq) + bias concat ----
    PrepArgs pa = { Wq, Wk, Wv, Wo, Wval, Wout, Woff, Watt, W1, W2,
                    WqkT, WvT, WoT, WvalT, WoutT, WoaT, W1T, W2T,
                    bq, bk, boff, batt, bqk, boa };
    prep_kernel<<<dim3(1529), blk, 0, stream>>>(pa);

    // ---- merged value | qk | v GEMMs ----
    addvec_kernel<<<dim3((n4+255)/256), blk, 0, stream>>>(tgt, qpos, qkin, n4);
    mgemm3_kernel<<<dim3(3070), blk512, 0, stream>>>(
        memory, WvalT, bval, valb,
        qkin, WqkT, bqk, qkb,
        tgt, WvT, bv, vb);

    // ---- stage 1: self-attention ----
    attn_mfma_kernel<<<dim3(512), blk, 0, stream>>>(qkb, vb, abuf);
    gemmln_kernel<float><<<dim3(113), blk512, 0, stream>>>(abuf, WoT, bo, tgt, ln2g, ln2b, tgt2, ROWS, CDIM);

    // ---- stage 2: deformable cross-attention ----
    addvec_kernel<<<dim3((n4+255)/256), blk, 0, stream>>>(tgt2, qpos, qkin, n4);
    gemm_mfma<float,0,float><<<dim3(4,57), blk512, 0, stream>>>(qkin, WoaT, boa, oab, ROWS, OAS, CDIM);
    msdeform_kernel<<<dim3(ROWS*NH/32), blk, 0, stream>>>(valb, oab, refpts, vbuf);
    gemmln_kernel<float><<<dim3(113), blk512, 0, stream>>>(vbuf, WoutT, bout, tgt2, ln1g, ln1b, tgt3, ROWS, CDIM);

    // ---- stage 3: FFN ----
    gemm_mfma<float,1,u16><<<dim3(16,57), blk512, 0, stream>>>(tgt3, W1T, b1, ffnh, ROWS, DFF, CDIM);
    gemmln_kernel<u16><<<dim3(113), blk512, 0, stream>>>(ffnh, W2T, b2, tgt3, ln3g, ln3b, out, ROWS, DFF);
}